// Round 2
// baseline (161.293 us; speedup 1.0000x reference)
//
#include <hip/hip_runtime.h>
#include <math.h>

// Problem constants (from reference):
//   B=8, R=50 (rafs has 2R=100 channels), C=150, H=W=128, N=4096, K=192
#define KPTS   192
#define RDIM   50
#define BDIM   8
#define HDIM   128
#define WDIM   128
#define NREL   4096
#define CDIM   150
#define LOSS_W 0.1f
#define WPB    4          // waves per block
#define PLANE  (HDIM * WDIM)
#define NPAIR  (BDIM * RDIM)   // 400 (bi, pred) plane-pairs
#define LISTSZ 512             // max relations per pair (E[n]=10.2, Poisson; 512 is unreachable)

// Stage 1 (rewritten): one block per (bi, pred) plane-pair.
//   1. scan rels (L2-resident, 128 KB) for relations matching this pair
//   2. stage the pair's TWO contiguous raf planes (128 KB) into LDS with
//      coalesced float4 loads -- converts ~35 MB of random 64B HBM gathers
//      into 51 MB of streaming reads at full BW
//   3. each wave processes one matching relation, sampling from LDS.
// Per-relation arithmetic is instruction-identical to the previously
// verified kernel (absmax=0): same clamp trick, same shfl-up dup check,
// same shuffle-tree reduction -- only the value source moved to LDS.
__global__ __launch_bounds__(256) void relation_lds_kernel(
    const float* __restrict__ rafs,      // (B, 2R, H, W)
    const float* __restrict__ heatmaps,  // (B, C, H, W)
    const int*   __restrict__ rels,      // (N, 8)
    float* __restrict__ ws)              // (N,) per-relation logp
{
    __shared__ float plane[2 * PLANE];   // 128 KB: channels 2*pred, 2*pred+1
    __shared__ int   list[LISTSZ];
    __shared__ int   lcnt;

    const int tid  = threadIdx.x;
    const int bi_b = blockIdx.x / RDIM;          // 0..7
    const int pr_b = blockIdx.x - bi_b * RDIM;   // 0..49

    if (tid == 0) lcnt = 0;
    __syncthreads();

    // ---- scan: find relations belonging to this (bi, pred) pair.
    // rels is 128 KB -> L2-hit for all but the first blocks per XCD.
    for (int i = tid; i < NREL; i += 256) {
        const int rbi = rels[i * 8 + 0];
        const int rpr = rels[i * 8 + 7];
        if (rbi == bi_b && rpr == pr_b) {
            const int p = atomicAdd(&lcnt, 1);
            if (p < LISTSZ) list[p] = i;
        }
    }

    // ---- stage: both planes are contiguous in memory (channel stride = PLANE,
    // channels 2p and 2p+1 adjacent) -> one 128 KB streaming copy.
    {
        const size_t rafbase =
            ((size_t)bi_b * (2 * RDIM) + (size_t)(2 * pr_b)) * (size_t)PLANE;
        const float4* __restrict__ src = (const float4*)(rafs + rafbase);
        float4* dst = (float4*)plane;
        #pragma unroll 8
        for (int i = tid; i < (2 * PLANE) / 4; i += 256)
            dst[i] = src[i];
    }
    __syncthreads();

    const int n    = lcnt;
    const int wave = tid >> 6;
    const int lane = tid & 63;

    for (int j = wave; j < n; j += WPB) {
        const int rel = __builtin_amdgcn_readfirstlane(list[j]);

        const int4* r4 = (const int4*)(rels + (size_t)rel * 8);
        const int4 ra = r4[0];   // bi, scls, sy, sx
        const int4 rb = r4[1];   // ocls, oy, ox, pred
        const int scls = __builtin_amdgcn_readfirstlane(ra.y);
        const int sy   = __builtin_amdgcn_readfirstlane(ra.z);
        const int sx   = __builtin_amdgcn_readfirstlane(ra.w);
        const int ocls = __builtin_amdgcn_readfirstlane(rb.x);
        const int oy   = __builtin_amdgcn_readfirstlane(rb.y);
        const int ox   = __builtin_amdgcn_readfirstlane(rb.z);

        // Scalar-address loads; latency overlaps the sampling phase below.
        const float subj = heatmaps[(((size_t)bi_b * CDIM + (size_t)scls) * HDIM + (size_t)sy) * WDIM + (size_t)sx];
        const float obj  = heatmaps[(((size_t)bi_b * CDIM + (size_t)ocls) * HDIM + (size_t)oy) * WDIM + (size_t)ox];

        const float dx = (float)(ox - sx);
        const float dy = (float)(oy - sy);
        const float norms = sqrtf(dx * dx + dy * dy);
        const float ux = dx / norms;
        const float uy = dy / norms;
        const int   num = (int)ceilf(norms);           // 1..180 < 192
        const float denom = (float)((num - 1) > 1 ? (num - 1) : 1);

        const float oxf = (float)ox, oyf = (float)oy;
        const float sxmox = (float)(sx - ox);
        const float symoy = (float)(sy - oy);

        // Phase 1: all sample points, all LDS reads (branchless; clamped
        // lanes re-read the num-1 sample -- same values as reference k=num-1).
        int   pxs[3], pys[3];
        float vxs[3], vys[3];
        #pragma unroll
        for (int s = 0; s < 3; ++s) {
            const int k  = lane + 64 * s;
            const int kk = (k < num) ? k : (num - 1);
            const float t  = (float)kk / denom;             // EXACT reference expr
            const int   px = (int)rintf(oxf + t * sxmox);
            const int   py = (int)rintf(oyf + t * symoy);
            pxs[s] = px;
            pys[s] = py;
            const int off = py * WDIM + px;
            vxs[s] = plane[off];
            vys[s] = plane[PLANE + off];
        }

        // Phase 2: masked accumulate; neighbor lane supplies bitwise-exact
        // previous px/py for the dup check.
        float dot  = 0.0f;
        int   vcnt = 0;
        int   px63 = -1, py63 = -1;
        #pragma unroll
        for (int s = 0; s < 3; ++s) {
            int pxp = __shfl_up(pxs[s], 1, 64);
            int pyp = __shfl_up(pys[s], 1, 64);
            if (lane == 0) { pxp = px63; pyp = py63; }
            px63 = __shfl(pxs[s], 63, 64);
            py63 = __shfl(pys[s], 63, 64);

            const int  k   = lane + 64 * s;
            const bool dup = (pxs[s] == pxp) && (pys[s] == pyp);
            if ((k < num) && !dup) {
                float vx = fminf(fmaxf(vxs[s], -1.0f), 1.0f);
                float vy = fminf(fmaxf(vys[s], -1.0f), 1.0f);
                dot  += vx * ux + vy * uy;
                vcnt += 1;
            }
        }

        // Wave64 shuffle reduction.
        #pragma unroll
        for (int off = 32; off > 0; off >>= 1) {
            dot  += __shfl_down(dot,  off, 64);
            vcnt += __shfl_down(vcnt, off, 64);
        }

        if (lane == 0) {
            float integral = dot / (float)vcnt;          // vcnt >= 1
            integral = fminf(fmaxf(integral, 0.0f), 1.0f);
            const float rs = subj * obj * integral;
            ws[rel] = logf(fmaxf(rs, 1e-12f));
        }
    }
}

// Stage 2: deterministic sum of NREL partials -> scalar loss. One block.
// (Unchanged -- verified bit-exact, absmax=0.)
__global__ __launch_bounds__(256) void reduce_kernel(
    const float* __restrict__ part,   // (NREL,)
    float* __restrict__ out)
{
    const int tid = threadIdx.x;
    float acc = 0.0f;
    #pragma unroll
    for (int j = 0; j < NREL / 256; ++j)
        acc += part[tid + j * 256];

    #pragma unroll
    for (int off = 32; off > 0; off >>= 1)
        acc += __shfl_down(acc, off, 64);

    __shared__ float s[4];
    const int wave = tid >> 6;
    const int lane = tid & 63;
    if (lane == 0) s[wave] = acc;
    __syncthreads();
    if (tid == 0) {
        const float total = s[0] + s[1] + s[2] + s[3];
        out[0] = total * (-LOSS_W / (float)NREL);
    }
}

extern "C" void kernel_launch(void* const* d_in, const int* in_sizes, int n_in,
                              void* d_out, int out_size, void* d_ws, size_t ws_size,
                              hipStream_t stream) {
    const float* rafs     = (const float*)d_in[0];
    const float* heatmaps = (const float*)d_in[1];
    const int*   rels     = (const int*)d_in[2];
    float*       out      = (float*)d_out;
    float*       part     = (float*)d_ws;

    relation_lds_kernel<<<NPAIR, 256, 0, stream>>>(rafs, heatmaps, rels, part);
    reduce_kernel<<<1, 256, 0, stream>>>(part, out);
}